// Round 1
// baseline (192.547 us; speedup 1.0000x reference)
//
#include <hip/hip_runtime.h>

#define NUMP 53149
#define NROWS (3*NUMP)            // 159447
#define BB 16
#define NK 68
#define HIMG 640
#define WIMG 360
#define NPIX (HIMG*WIMG)          // 230400
#define GS_IDX 26574

// workspace offsets (bytes)
#define OCC_OFF 0
#define OCC_BYTES (BB*NPIX)            // 3,686,400
#define GS_OFF   OCC_BYTES
#define SUM_OFF  (GS_OFF + BB*4)
#define CNT_OFF  (SUM_OFF + BB*4)
#define ZERO_BYTES (CNT_OFF + BB*4)    // memset [0, ZERO_BYTES)
#define R1_OFF   ZERO_BYTES
#define PTS_OFF  (R1_OFF + 576)

// output offsets (floats)
#define O_LK   0
#define O_LK1  1
#define O_LREG 2
#define O_LD   3
#define O_R1   4
#define O_T    148
#define O_PK2  196
#define O_MASK 2372
#define O_PRED (O_MASK + BB*NPIX)      // 3,688,772

// ---------------- Kernel 1: points0 = mean + pca @ (param*sqrt(var)) ----------------
__global__ void k_points0(const float* __restrict__ mean, const float* __restrict__ pca,
                          const float* __restrict__ variance, const float* __restrict__ param,
                          float* __restrict__ pts0) {
    __shared__ float coef[80];
    int t = threadIdx.x;
    if (t < 80) coef[t] = param[t] * sqrtf(variance[t]);
    __syncthreads();
    int r = blockIdx.x * 256 + t;
    if (r >= NROWS) return;
    const float4* row = (const float4*)(pca + (size_t)r * 80);
    float s = 0.f;
#pragma unroll
    for (int k = 0; k < 20; ++k) {
        float4 v = row[k];
        s += v.x * coef[4*k+0] + v.y * coef[4*k+1] + v.z * coef[4*k+2] + v.w * coef[4*k+3];
    }
    pts0[r] = mean[r] + s;
}

// ---------------- Kernel 2: R1, T, pk2, loss_k, loss_k1, loss_reg ----------------
__global__ void k_keypoints(const float* __restrict__ R_in, const float* __restrict__ T_in,
                            const int* __restrict__ key_kp, const float* __restrict__ key_ref,
                            const float* __restrict__ key_side_ref, const float* __restrict__ param,
                            const float* __restrict__ pts0,
                            float* __restrict__ out, float* __restrict__ R1ws) {
    __shared__ float R1s[BB][9];
    __shared__ float pk2s[BB*NK*2];
    __shared__ float red[256];
    int t = threadIdx.x;

    if (t < BB) {
        float ax = R_in[t*3+0], ay = R_in[t*3+1], az = R_in[t*3+2];
        float sx = sinf(ax), cx = cosf(ax);
        float sy = sinf(ay), cy = cosf(ay);
        float sz = sinf(az), cz = cosf(az);
        float r00 = cz*cy, r01 = cz*sy*sx - sz*cx, r02 = cz*sy*cx + sz*sx;
        float r10 = sz*cy, r11 = sz*sy*sx + cz*cx, r12 = sz*sy*cx - cz*sx;
        float r20 = -sy,   r21 = cy*sx,            r22 = cy*cx;
        float rv[9] = {r00,r01,r02,r10,r11,r12,r20,r21,r22};
#pragma unroll
        for (int i = 0; i < 9; ++i) {
            R1s[t][i] = rv[i];
            out[O_R1 + t*9 + i] = rv[i];
            R1ws[t*9 + i] = rv[i];
        }
        out[O_T + t*3+0] = T_in[t*3+0];
        out[O_T + t*3+1] = T_in[t*3+1];
        out[O_T + t*3+2] = T_in[t*3+2];
    }
    __syncthreads();

    for (int idx = t; idx < BB*NK; idx += 256) {
        int b = idx / NK, k = idx % NK;
        int kk = key_kp[k];
        float px = pts0[kk*3+0], py = pts0[kk*3+1], pz = pts0[kk*3+2];
        const float* R = R1s[b];
        float X = px*R[0] + py*R[3] + pz*R[6] + T_in[b*3+0];
        float Y = px*R[1] + py*R[4] + pz*R[7] + T_in[b*3+1];
        float Z = px*R[2] + py*R[5] + pz*R[8] + T_in[b*3+2];
        float zz = -Z;
        float u = (436.16f*X + 179.22f*zz) / zz;
        float v = (436.16f*Y + 320.08f*zz) / zz;
        pk2s[idx*2+0] = u; pk2s[idx*2+1] = v;
        out[O_PK2 + idx*2+0] = u;
        out[O_PK2 + idx*2+1] = v;
    }
    __syncthreads();

    // loss_k over INNER (52): j==0 -> 8 else 16+j
    float accK = 0.f;
    for (int idx = t; idx < BB*52; idx += 256) {
        int b = idx / 52, j = idx % 52;
        int ik = (j == 0) ? 8 : (16 + j);
        float dx = pk2s[(b*NK + ik)*2+0] - key_ref[idx*2+0];
        float dy = pk2s[(b*NK + ik)*2+1] - key_ref[idx*2+1];
        accK += dx*dx + dy*dy;
    }
    // loss_k1 over SIDE (16): j<8 -> j else j+1  (BB*16 == 256 exactly)
    float accS = 0.f;
    {
        int b = t / 16, j = t % 16;
        int is_ = (j < 8) ? j : (j + 1);
        float dx = pk2s[(b*NK + is_)*2+0] - key_side_ref[t*2+0];
        float dy = pk2s[(b*NK + is_)*2+1] - key_side_ref[t*2+1];
        accS = dx*dx + dy*dy;
    }
    float accR = (t < 80) ? param[t]*param[t] : 0.f;

    red[t] = accK; __syncthreads();
    for (int s = 128; s > 0; s >>= 1) { if (t < s) red[t] += red[t+s]; __syncthreads(); }
    float sK = red[0]; __syncthreads();

    red[t] = accS; __syncthreads();
    for (int s = 128; s > 0; s >>= 1) { if (t < s) red[t] += red[t+s]; __syncthreads(); }
    float sS = red[0]; __syncthreads();

    red[t] = accR; __syncthreads();
    for (int s = 128; s > 0; s >>= 1) { if (t < s) red[t] += red[t+s]; __syncthreads(); }
    float sR = red[0];

    if (t == 0) {
        out[O_LK]   = sK / (float)(BB*52*2);
        out[O_LK1]  = sS / (float)(BB*16*2);
        out[O_LREG] = sR / 80.f;
    }
}

// ---------------- Kernel 3: transform all points, occupancy scatter, gs extract ----------------
__global__ void k_scatter(const float* __restrict__ pts0, const float* __restrict__ R1ws,
                          const float* __restrict__ T_in,
                          unsigned char* __restrict__ occ, float* __restrict__ gs) {
    int n = blockIdx.x * 256 + threadIdx.x;
    int b = blockIdx.y;
    if (n >= NUMP) return;
    const float* R = R1ws + b*9;
    float px = pts0[n*3+0], py = pts0[n*3+1], pz = pts0[n*3+2];
    float X = px*R[0] + py*R[3] + pz*R[6] + T_in[b*3+0];
    float Y = px*R[1] + py*R[4] + pz*R[7] + T_in[b*3+1];
    float Z = px*R[2] + py*R[5] + pz*R[8] + T_in[b*3+2];
    float zz = -Z;
    float u = (436.16f*X + 179.22f*zz) / zz;
    float v = (436.16f*Y + 320.08f*zz) / zz;
    bool m0 = (v >= 0.f) && (v <= (float)(HIMG-1)) && (u >= 0.f) && (u <= (float)(WIMG-1));
    float mf = m0 ? 1.f : 0.f;
    u *= mf; v *= mf;
    int xi = (int)u;
    int yi = (int)v;
    occ[(size_t)b*NPIX + yi*WIMG + xi] = 1;
    if (n == GS_IDX) gs[b] = v;  // p1[b, 26574, 1] after masking
}

// ---------------- Kernel 4: depth losses + mask/pred_d outputs ----------------
__global__ void k_depth(const unsigned char* __restrict__ occ, const float* __restrict__ refd,
                        const float* __restrict__ gs, const int* __restrict__ dptr,
                        float* __restrict__ mask_out, float* __restrict__ pred_out,
                        float* __restrict__ sum_ld, int* __restrict__ cnt) {
    int b = blockIdx.y;
    int i4 = (blockIdx.x * 256 + threadIdx.x) * 4;   // 225*256*4 == NPIX exactly
    float g = gs[b];
    int w = *dptr;
    float dv = (w >= 0 && w < (1 << 23)) ? (float)w : __int_as_float(w);

    size_t base = (size_t)b * NPIX + i4;
    float4 rd = *(const float4*)(refd + base);
    uchar4 oc = *(const uchar4*)(occ + base);

    float lsum = 0.f; int lcnt = 0;
    float4 mo, po;
    {
        float occf = oc.x ? 1.f : 0.f;
        float pred = g * occf, rm = rd.x * occf;
        float df = pred - rm, ld = df * df;
        bool mk = (ld < dv) && (ld > 1e-6f) && (pred > 0.f);
        float ldz = ((ld > dv) || (pred < 1e-5f)) ? 0.f : ld;
        mo.x = mk ? 1.f : 0.f; po.x = pred; lsum += ldz; lcnt += mk;
    }
    {
        float occf = oc.y ? 1.f : 0.f;
        float pred = g * occf, rm = rd.y * occf;
        float df = pred - rm, ld = df * df;
        bool mk = (ld < dv) && (ld > 1e-6f) && (pred > 0.f);
        float ldz = ((ld > dv) || (pred < 1e-5f)) ? 0.f : ld;
        mo.y = mk ? 1.f : 0.f; po.y = pred; lsum += ldz; lcnt += mk;
    }
    {
        float occf = oc.z ? 1.f : 0.f;
        float pred = g * occf, rm = rd.z * occf;
        float df = pred - rm, ld = df * df;
        bool mk = (ld < dv) && (ld > 1e-6f) && (pred > 0.f);
        float ldz = ((ld > dv) || (pred < 1e-5f)) ? 0.f : ld;
        mo.z = mk ? 1.f : 0.f; po.z = pred; lsum += ldz; lcnt += mk;
    }
    {
        float occf = oc.w ? 1.f : 0.f;
        float pred = g * occf, rm = rd.w * occf;
        float df = pred - rm, ld = df * df;
        bool mk = (ld < dv) && (ld > 1e-6f) && (pred > 0.f);
        float ldz = ((ld > dv) || (pred < 1e-5f)) ? 0.f : ld;
        mo.w = mk ? 1.f : 0.f; po.w = pred; lsum += ldz; lcnt += mk;
    }
    *(float4*)(mask_out + base) = mo;
    *(float4*)(pred_out + base) = po;

    // block reduction: wave shuffle then LDS
#pragma unroll
    for (int off = 32; off > 0; off >>= 1) {
        lsum += __shfl_down(lsum, off, 64);
        lcnt += __shfl_down(lcnt, off, 64);
    }
    __shared__ float sred[4];
    __shared__ int   cred[4];
    int lane = threadIdx.x & 63, wid = threadIdx.x >> 6;
    if (lane == 0) { sred[wid] = lsum; cred[wid] = lcnt; }
    __syncthreads();
    if (threadIdx.x == 0) {
        float s = sred[0] + sred[1] + sred[2] + sred[3];
        int   c = cred[0] + cred[1] + cred[2] + cred[3];
        atomicAdd(&sum_ld[b], s);
        atomicAdd(&cnt[b], c);
    }
}

// ---------------- Kernel 5: final loss_d ----------------
__global__ void k_lossd(const float* __restrict__ sum_ld, const int* __restrict__ cnt,
                        float* __restrict__ out) {
    if (threadIdx.x == 0) {
        float a = 0.f;
        for (int b = 0; b < BB; ++b) a += sum_ld[b] / ((float)cnt[b] + 1.f);
        out[O_LD] = a / (float)BB;
    }
}

extern "C" void kernel_launch(void* const* d_in, const int* in_sizes, int n_in,
                              void* d_out, int out_size, void* d_ws, size_t ws_size,
                              hipStream_t stream) {
    const float* mean         = (const float*)d_in[0];
    const float* pca          = (const float*)d_in[1];
    const float* variance     = (const float*)d_in[2];
    const float* param        = (const float*)d_in[3];
    const float* R_in         = (const float*)d_in[4];
    const float* T_in         = (const float*)d_in[5];
    const int*   key_kp       = (const int*)d_in[6];
    const float* key_ref      = (const float*)d_in[7];
    const float* key_side_ref = (const float*)d_in[8];
    const float* ref_depth    = (const float*)d_in[9];
    const int*   dptr         = (const int*)d_in[10];

    float* out = (float*)d_out;
    char*  ws  = (char*)d_ws;
    unsigned char* occ = (unsigned char*)(ws + OCC_OFF);
    float* gs     = (float*)(ws + GS_OFF);
    float* sum_ld = (float*)(ws + SUM_OFF);
    int*   cnt    = (int*)(ws + CNT_OFF);
    float* R1ws   = (float*)(ws + R1_OFF);
    float* pts0   = (float*)(ws + PTS_OFF);

    hipMemsetAsync(ws, 0, ZERO_BYTES, stream);

    k_points0<<<dim3((NROWS + 255) / 256), 256, 0, stream>>>(mean, pca, variance, param, pts0);
    k_keypoints<<<1, 256, 0, stream>>>(R_in, T_in, key_kp, key_ref, key_side_ref, param, pts0, out, R1ws);
    k_scatter<<<dim3((NUMP + 255) / 256, BB), 256, 0, stream>>>(pts0, R1ws, T_in, occ, gs);
    k_depth<<<dim3(225, BB), 256, 0, stream>>>(occ, ref_depth, gs, dptr,
                                               out + O_MASK, out + O_PRED, sum_ld, cnt);
    k_lossd<<<1, 64, 0, stream>>>(sum_ld, cnt, out);
}